// Round 10
// baseline (250.360 us; speedup 1.0000x reference)
//
#include <hip/hip_runtime.h>
#include <hip/hip_bf16.h>
#include <math.h>

#define NUM_CLASSES 124
#define NCLS_PAD    128
#define FEAT_CH     64
#define OUT_HW      480
#define IN_HW       120
#define NPIX        (OUT_HW * OUT_HW)
#define NCELL       (IN_HW * IN_HW)
#define NCHUNK      (NPIX / 32)         // 7200 chunks of 32 px
#define EPSV        1e-8f

#define STRIDE_ACC   65
#define ACC_FLOATS   (NCLS_PAD * STRIDE_ACC)           // 8320
#define ACC_TOTAL    (ACC_FLOATS + NCLS_PAD)           // 8448
#define MN_STRIDE    65                                // bf16 shorts, bank-spread

#define NB          450                 // 450*8 = 3600 waves -> exactly 2 chunks each

typedef short  v8s __attribute__((ext_vector_type(8)));
typedef float  v4f __attribute__((ext_vector_type(4)));

__device__ __forceinline__ short f2bf(float x) {
    __hip_bfloat16 h = __float2bfloat16(x);
    return __builtin_bit_cast(short, h);
}
__device__ __forceinline__ float bf2f(short s) {
    return __int_as_float(((int)s) << 16);
}

template <int CTRL>
__device__ __forceinline__ float dpp_ror_add(float x) {
    int v = __builtin_amdgcn_update_dpp(0, __float_as_int(x), CTRL, 0xF, 0xF, false);
    return x + __int_as_float(v);
}
__device__ __forceinline__ void reduce16_pair(float& a, float& b) {
    a = dpp_ror_add<0x128>(a); b = dpp_ror_add<0x128>(b);   // row_ror:8
    a = dpp_ror_add<0x124>(a); b = dpp_ror_add<0x124>(b);   // row_ror:4
    a = dpp_ror_add<0x122>(a); b = dpp_ror_add<0x122>(b);   // row_ror:2
    a = dpp_ror_add<0x121>(a); b = dpp_ror_add<0x121>(b);   // row_ror:1
}

// Single kernel: per-block mn->LDS, one-hot MFMA accumulate (direct feats reads),
// global-atomic flush, last-block finalize (agent-scope coherent reads).
__global__ __launch_bounds__(512, 2) void k_main(
        const float* __restrict__ feats, const float* __restrict__ mem,
        const int* __restrict__ seg, float* __restrict__ out,
        float* __restrict__ acc, int* __restrict__ counter) {
    __shared__ float accL[ACC_FLOATS];                 // 33280 B
    __shared__ short mnL[NUM_CLASSES * MN_STRIDE];     // 16120 B
    __shared__ float cntL[NCLS_PAD];
    __shared__ int   lastL;

    const int tid  = threadIdx.x;
    const int lane = tid & 63;
    const int widx = tid >> 6;        // wave in block (0..7)
    const int n  = lane & 15;         // ch within tile / class within band
    const int kg = lane >> 4;         // pixel-group (8 px each)

    // ---- per-block prep: normalized memory rows -> mnL (bf16); zero accL -----
    for (int c = widx; c < NUM_CLASSES; c += 8) {
        float v = mem[c * FEAT_CH + lane];
        float s = v * v;
#pragma unroll
        for (int off = 32; off; off >>= 1) s += __shfl_xor(s, off);
        mnL[c * MN_STRIDE + lane] = f2bf(v / fmaxf(sqrtf(s), EPSV));
    }
    for (int i = tid; i < ACC_FLOATS; i += 512) accL[i] = 0.0f;
    if (tid < NCLS_PAD) cntL[tid] = 0.0f;
    __syncthreads();

    // ---- MFMA accumulation loop ----------------------------------------------
    const int gwave = blockIdx.x * 8 + widx;
    v4f accR[8][4];
#pragma unroll
    for (int b = 0; b < 8; ++b)
#pragma unroll
        for (int t = 0; t < 4; ++t) accR[b][t] = (v4f)0.0f;

    for (int ch = gwave; ch < NCHUNK; ch += NB * 8) {
        const int oy  = ch / 15;
        const int px0 = (ch - oy * 15) * 32 + kg * 8;
        float fy = fminf(fmaxf(oy * 0.25f - 0.375f, 0.0f), 119.0f);
        const int y0 = (int)fy; const float ty = fy - (float)y0;
        const int y1 = min(y0 + 1, IN_HW - 1);
        const int base = px0 >> 2;
        const int c0 = max(base - 1, 0), c1 = base;
        const int c2 = min(base + 1, IN_HW - 1), c3 = min(base + 2, IN_HW - 1);
        const int r0 = y0 * IN_HW, r1 = y1 * IN_HW;

        int segj[8];
        {
            const int4* sp = (const int4*)(seg + oy * OUT_HW + px0);
            int4 s0 = sp[0], s1 = sp[1];
            segj[0]=s0.x; segj[1]=s0.y; segj[2]=s0.z; segj[3]=s0.w;
            segj[4]=s1.x; segj[5]=s1.y; segj[6]=s1.z; segj[7]=s1.w;
        }
        float txj[8]; int Lj[8];
#pragma unroll
        for (int j = 0; j < 8; ++j) {
            float fx = fminf(fmaxf((float)(px0 + j) * 0.25f - 0.375f, 0.0f), 119.0f);
            int x0 = (int)fx; txj[j] = fx - (float)x0; Lj[j] = x0 - base + 1;  // 0..2
        }

        float nr[8], dt[8];
#pragma unroll
        for (int j = 0; j < 8; ++j) { nr[j] = 0.0f; dt[j] = 0.0f; }
        v8s Bfrag[4];
#pragma unroll
        for (int t = 0; t < 4; ++t) {
            const int chn = n + 16 * t;
            const float* __restrict__ pf = feats + chn * NCELL;   // direct read, L2-resident
            const float T0 = pf[r0+c0], T1 = pf[r0+c1], T2 = pf[r0+c2], T3 = pf[r0+c3];
            const float B0 = pf[r1+c0], B1 = pf[r1+c1], B2 = pf[r1+c2], B3 = pf[r1+c3];
#pragma unroll
            for (int j = 0; j < 8; ++j) {
                const int L = Lj[j];
                float tl = (L==0)?T0:((L==1)?T1:T2);
                float tr = (L==0)?T1:((L==1)?T2:T3);
                float bl = (L==0)?B0:((L==1)?B1:B2);
                float br = (L==0)?B1:((L==1)?B2:B3);
                float top = fmaf(txj[j], tr - tl, tl);
                float bot = fmaf(txj[j], br - bl, bl);
                float v   = fmaf(ty, bot - top, top);
                nr[j] = fmaf(v, v, nr[j]);
                dt[j] = fmaf(v, bf2f(mnL[segj[j] * MN_STRIDE + chn]), dt[j]);
                Bfrag[t][j] = f2bf(v);
            }
        }
#pragma unroll
        for (int j = 0; j < 8; ++j) reduce16_pair(nr[j], dt[j]);

        float wj[8]; short wb[8];
#pragma unroll
        for (int j = 0; j < 8; ++j) {
            wj[j] = 1.0f - dt[j] / fmaxf(sqrtf(nr[j]), EPSV);  // mn==0 rows -> w==1
            wb[j] = f2bf(wj[j]);
        }
#pragma unroll
        for (int b = 0; b < 8; ++b) {
            v8s A;
#pragma unroll
            for (int j = 0; j < 8; ++j)
                A[j] = (segj[j] == b * 16 + n) ? wb[j] : (short)0;
#pragma unroll
            for (int t = 0; t < 4; ++t)
                accR[b][t] = __builtin_amdgcn_mfma_f32_16x16x32_bf16(A, Bfrag[t], accR[b][t], 0, 0, 0);
        }
        if (n == 0) {
#pragma unroll
            for (int j = 0; j < 8; ++j) {
                atomicAdd(&accL[segj[j] * STRIDE_ACC + FEAT_CH], wj[j]);
                atomicAdd(&cntL[segj[j]], 1.0f);
            }
        }
    }
    __syncthreads();

    // ---- staggered band merge: step s, wave w -> band (w+s)&7 (disjoint) -----
    for (int s = 0; s < 8; ++s) {
        const int b = (widx + s) & 7;
#pragma unroll
        for (int t = 0; t < 4; ++t)
#pragma unroll
            for (int r = 0; r < 4; ++r) {
                const int cls = b * 16 + kg * 4 + r;
                const int chn = t * 16 + n;
                accL[cls * STRIDE_ACC + chn] += accR[b][t][r];
            }
        __syncthreads();
    }

    // ---- flush via device-scope atomics (staggered start, skip zeros) --------
    {
        const int off = (int)((blockIdx.x * 2017u) % ACC_FLOATS);
        for (int i0 = tid; i0 < ACC_FLOATS; i0 += 512) {
            int i = i0 + off; if (i >= ACC_FLOATS) i -= ACC_FLOATS;
            float v = accL[i];
            if (v != 0.0f) atomicAdd(&acc[i], v);
        }
        for (int i = tid; i < NCLS_PAD; i += 512) {
            float v = cntL[i];
            if (v != 0.0f) atomicAdd(&acc[ACC_FLOATS + i], v);
        }
    }
    __threadfence();
    __syncthreads();
    if (tid == 0) {
        int old = __hip_atomic_fetch_add(counter, 1, __ATOMIC_ACQ_REL,
                                         __HIP_MEMORY_SCOPE_AGENT);
        lastL = (old == NB - 1) ? 1 : 0;
    }
    __syncthreads();

    // ---- last block finalizes: momentum / is_zero / present ------------------
    if (lastL) {
        for (int c = widx; c < NUM_CLASSES; c += 8) {
            const int k = lane;
            const float a    = __hip_atomic_load(&acc[c * STRIDE_ACC + k],
                                __ATOMIC_RELAXED, __HIP_MEMORY_SCOPE_AGENT);
            const float wsum = __hip_atomic_load(&acc[c * STRIDE_ACC + FEAT_CH],
                                __ATOMIC_RELAXED, __HIP_MEMORY_SCOPE_AGENT);
            const float cnt  = __hip_atomic_load(&acc[ACC_FLOATS + c],
                                __ATOMIC_RELAXED, __HIP_MEMORY_SCOPE_AGENT);
            const float m = mem[c * FEAT_CH + k];
            const int is_zero = __all(m == 0.0f);          // wave = the 64 channels
            const float divisor = (wsum > 0.0f) ? wsum : 1.0f;
            const float val = a / divisor;
            const float nw = is_zero ? val : fmaf(0.1f, val, 0.9f * m);
            out[c * FEAT_CH + k] = (cnt > 0.0f) ? nw : m;
        }
    }
}

extern "C" void kernel_launch(void* const* d_in, const int* in_sizes, int n_in,
                              void* d_out, int out_size, void* d_ws, size_t ws_size,
                              hipStream_t stream) {
    const float* feats  = (const float*)d_in[0];   // (1,64,120,120) f32
    const float* memory = (const float*)d_in[1];   // (124,1,64) f32
    const int*   seg    = (const int*)d_in[2];     // (1,480,480) i32
    float* out = (float*)d_out;                    // (124,1,64) f32
    float* acc = (float*)d_ws;                     // 8448 floats
    int*   cnt = (int*)((float*)d_ws + ACC_TOTAL); // 1 int

    hipMemsetAsync(d_ws, 0, (ACC_TOTAL + 1) * sizeof(float), stream);
    k_main<<<NB, 512, 0, stream>>>(feats, memory, seg, out, acc, cnt);
}

// Round 11
// 173.467 us; speedup vs baseline: 1.4433x; 1.4433x over previous
//
#include <hip/hip_runtime.h>
#include <hip/hip_bf16.h>
#include <math.h>

#define NUM_CLASSES 124
#define NCLS_PAD    128
#define FEAT_CH     64
#define OUT_HW      480
#define IN_HW       120
#define NPIX        (OUT_HW * OUT_HW)
#define NCELL       (IN_HW * IN_HW)
#define NCHUNK      (NPIX / 32)         // 7200 chunks of 32 px
#define EPSV        1e-8f

#define STRIDE_ACC   65                 // LDS accumulator stride (floats)
#define ACC_FLOATS   (NCLS_PAD * STRIDE_ACC)           // 8320
#define PART_ROW     66                 // part slice: 64 ch + wsum + cnt per class
#define PART_SLICE   (NCLS_PAD * PART_ROW)             // 8448 floats
#define NB          450                 // 450*8 = 3600 waves -> exactly 2 chunks each
#define NTILE       (NCELL / 64)        // 225 transpose tiles

// ws layout (floats): mn_bf[3968 (7936 shorts)] | fT[921600] | part[450*8448]
#define WS_MNBF 0
#define WS_FT   4096
#define WS_PART (WS_FT + NCELL * FEAT_CH)

typedef short  v8s __attribute__((ext_vector_type(8)));
typedef float  v4f __attribute__((ext_vector_type(4)));

__device__ __forceinline__ short f2bf(float x) {
    __hip_bfloat16 h = __float2bfloat16(x);
    return __builtin_bit_cast(short, h);
}
__device__ __forceinline__ float bf2f(short s) {
    return __int_as_float(((int)s) << 16);
}

template <int CTRL>
__device__ __forceinline__ float dpp_ror_add(float x) {
    int v = __builtin_amdgcn_update_dpp(0, __float_as_int(x), CTRL, 0xF, 0xF, false);
    return x + __int_as_float(v);
}
__device__ __forceinline__ void reduce16_pair(float& a, float& b) {
    a = dpp_ror_add<0x128>(a); b = dpp_ror_add<0x128>(b);   // row_ror:8
    a = dpp_ror_add<0x124>(a); b = dpp_ror_add<0x124>(b);   // row_ror:4
    a = dpp_ror_add<0x122>(a); b = dpp_ror_add<0x122>(b);   // row_ror:2
    a = dpp_ror_add<0x121>(a); b = dpp_ror_add<0x121>(b);   // row_ror:1
}

// ---- phase 0: LDS-tiled transpose feats -> fT; normalize memory -> mn (bf16) -
__global__ __launch_bounds__(256) void k_prep(
        const float* __restrict__ mem, const float* __restrict__ feats,
        short* __restrict__ mn_bf, float* __restrict__ fT) {
    const int b = blockIdx.x;
    if (b < NTILE) {
        __shared__ float tileL[64 * 65];
        const int q0 = b * 64;
        const int tid = threadIdx.x;
#pragma unroll
        for (int i = 0; i < 16; ++i) {
            const int idx = i * 256 + tid;
            const int k = idx >> 6, q = idx & 63;  // q fast -> coalesced read
            tileL[q * 65 + k] = feats[k * NCELL + q0 + q];
        }
        __syncthreads();
#pragma unroll
        for (int i = 0; i < 16; ++i) {
            const int idx = i * 256 + tid;
            const int q = idx >> 6, k = idx & 63;  // k fast -> coalesced write
            fT[(q0 + q) * FEAT_CH + k] = tileL[q * 65 + k];
        }
    } else {
        if (threadIdx.x < FEAT_CH) {
            const int c = b - NTILE;               // 0..123
            float v = mem[c * FEAT_CH + threadIdx.x];
            float s = v * v;
#pragma unroll
            for (int off = 32; off; off >>= 1) s += __shfl_xor(s, off);
            mn_bf[c * FEAT_CH + threadIdx.x] = f2bf(v / fmaxf(sqrtf(s), EPSV));
        }
    }
}

// ---- phase 1: one-hot MFMA accumulation; plain part-slice stores -------------
__global__ __launch_bounds__(512, 2) void k_accum(
        const float* __restrict__ fT, const int* __restrict__ seg,
        const short* __restrict__ mn_bf, float* __restrict__ part) {
    __shared__ float accL[ACC_FLOATS];                 // 33280 B
    __shared__ short mnL[NUM_CLASSES * 65];            // 16120 B, stride 65 shorts
    __shared__ float cntL[NCLS_PAD];

    const int tid = threadIdx.x;
    for (int i = tid; i < ACC_FLOATS; i += 512) accL[i] = 0.0f;
    for (int i = tid; i < NUM_CLASSES * FEAT_CH; i += 512)
        mnL[(i >> 6) * 65 + (i & 63)] = mn_bf[i];
    if (tid < NCLS_PAD) cntL[tid] = 0.0f;
    __syncthreads();

    const int lane = tid & 63;
    const int n  = lane & 15;         // ch within tile / class within band
    const int kg = lane >> 4;         // pixel-group (8 px each)
    const int widx = tid >> 6;        // wave in block (0..7)
    const int gwave = blockIdx.x * 8 + widx;

    v4f accR[8][4];
#pragma unroll
    for (int b = 0; b < 8; ++b)
#pragma unroll
        for (int t = 0; t < 4; ++t) accR[b][t] = (v4f)0.0f;

    for (int ch = gwave; ch < NCHUNK; ch += NB * 8) {   // exactly 2 iterations
        const int oy  = ch / 15;
        const int px0 = (ch - oy * 15) * 32 + kg * 8;
        float fy = fminf(fmaxf(oy * 0.25f - 0.375f, 0.0f), 119.0f);
        const int y0 = (int)fy; const float ty = fy - (float)y0;
        const int y1 = min(y0 + 1, IN_HW - 1);
        const int base = px0 >> 2;
        const int c0 = max(base - 1, 0), c1 = base;
        const int c2 = min(base + 1, IN_HW - 1), c3 = min(base + 2, IN_HW - 1);
        const int r0 = y0 * IN_HW, r1 = y1 * IN_HW;

        int segj[8];
        {
            const int4* sp = (const int4*)(seg + oy * OUT_HW + px0);
            int4 s0 = sp[0], s1 = sp[1];
            segj[0]=s0.x; segj[1]=s0.y; segj[2]=s0.z; segj[3]=s0.w;
            segj[4]=s1.x; segj[5]=s1.y; segj[6]=s1.z; segj[7]=s1.w;
        }
        float txj[8]; int Lj[8];
#pragma unroll
        for (int j = 0; j < 8; ++j) {
            float fx = fminf(fmaxf((float)(px0 + j) * 0.25f - 0.375f, 0.0f), 119.0f);
            int x0 = (int)fx; txj[j] = fx - (float)x0; Lj[j] = x0 - base + 1;  // 0..2
        }

        float nr[8], dt[8];
#pragma unroll
        for (int j = 0; j < 8; ++j) { nr[j] = 0.0f; dt[j] = 0.0f; }
        v8s Bfrag[4];
#pragma unroll
        for (int t = 0; t < 4; ++t) {
            const int chn = n + 16 * t;
            const float T0 = fT[(r0+c0)*64+chn], T1 = fT[(r0+c1)*64+chn];
            const float T2 = fT[(r0+c2)*64+chn], T3 = fT[(r0+c3)*64+chn];
            const float B0 = fT[(r1+c0)*64+chn], B1 = fT[(r1+c1)*64+chn];
            const float B2 = fT[(r1+c2)*64+chn], B3 = fT[(r1+c3)*64+chn];
#pragma unroll
            for (int j = 0; j < 8; ++j) {
                const int L = Lj[j];
                float tl = (L==0)?T0:((L==1)?T1:T2);
                float tr = (L==0)?T1:((L==1)?T2:T3);
                float bl = (L==0)?B0:((L==1)?B1:B2);
                float br = (L==0)?B1:((L==1)?B2:B3);
                float top = fmaf(txj[j], tr - tl, tl);
                float bot = fmaf(txj[j], br - bl, bl);
                float v   = fmaf(ty, bot - top, top);
                nr[j] = fmaf(v, v, nr[j]);
                dt[j] = fmaf(v, bf2f(mnL[segj[j] * 65 + chn]), dt[j]);
                Bfrag[t][j] = f2bf(v);
            }
        }
#pragma unroll
        for (int j = 0; j < 8; ++j) reduce16_pair(nr[j], dt[j]);

        float wj[8]; short wb[8];
#pragma unroll
        for (int j = 0; j < 8; ++j) {
            wj[j] = 1.0f - dt[j] / fmaxf(sqrtf(nr[j]), EPSV);  // mn==0 rows -> w==1
            wb[j] = f2bf(wj[j]);
        }
#pragma unroll
        for (int b = 0; b < 8; ++b) {
            v8s A;
#pragma unroll
            for (int j = 0; j < 8; ++j)
                A[j] = (segj[j] == b * 16 + n) ? wb[j] : (short)0;
#pragma unroll
            for (int t = 0; t < 4; ++t)
                accR[b][t] = __builtin_amdgcn_mfma_f32_16x16x32_bf16(A, Bfrag[t], accR[b][t], 0, 0, 0);
        }
        if (n == 0) {
#pragma unroll
            for (int j = 0; j < 8; ++j) {
                atomicAdd(&accL[segj[j] * STRIDE_ACC + FEAT_CH], wj[j]);
                atomicAdd(&cntL[segj[j]], 1.0f);
            }
        }
    }
    __syncthreads();

    // staggered band merge: step s, wave w -> band (w+s)&7 (disjoint, no atomics)
    for (int s = 0; s < 8; ++s) {
        const int b = (widx + s) & 7;
#pragma unroll
        for (int t = 0; t < 4; ++t)
#pragma unroll
            for (int r = 0; r < 4; ++r) {
                const int cls = b * 16 + kg * 4 + r;
                const int chn = t * 16 + n;
                accL[cls * STRIDE_ACC + chn] += accR[b][t][r];
            }
        __syncthreads();
    }

    // plain coalesced store of this block's partial (stride-66: ch[64], wsum, cnt)
    float* __restrict__ dst = part + (size_t)blockIdx.x * PART_SLICE;
    for (int idx = tid; idx < PART_SLICE; idx += 512) {
        const int c = idx / PART_ROW, k = idx - c * PART_ROW;
        dst[idx] = (k < 65) ? accL[c * STRIDE_ACC + k] : cntL[c];
    }
}

// ---- phase 2 (fused): reduce 450 partials + momentum / is_zero / present -----
__global__ __launch_bounds__(512) void k_redfinal(
        const float* __restrict__ part, const float* __restrict__ mem,
        float* __restrict__ out) {
    __shared__ float sumL[8 * 64];
    __shared__ float extraL[16];
    const int c = blockIdx.x;                  // class
    const int tid = threadIdx.x;
    const int lane = tid & 63, p8 = tid >> 6;  // p8 in 0..7

    float sa = 0.0f;
    for (int p = p8; p < NB; p += 8)
        sa += part[(size_t)p * PART_SLICE + c * PART_ROW + lane];
    sumL[p8 * 64 + lane] = sa;
    if (tid < 16) {
        const int pb = tid & 7, slot = 64 + (tid >> 3);   // 64=wsum, 65=cnt
        float s = 0.0f;
        for (int p = pb; p < NB; p += 8)
            s += part[(size_t)p * PART_SLICE + c * PART_ROW + slot];
        extraL[tid] = s;
    }
    __syncthreads();

    if (tid < 64) {
        const int k = tid;
        float a = 0.0f;
#pragma unroll
        for (int q = 0; q < 8; ++q) a += sumL[q * 64 + k];
        float wsum = 0.0f, cnt = 0.0f;
#pragma unroll
        for (int q = 0; q < 8; ++q) { wsum += extraL[q]; cnt += extraL[8 + q]; }
        const float m = mem[c * FEAT_CH + k];
        const int is_zero = __all(m == 0.0f);           // full wave = the 64 channels
        const float divisor = (wsum > 0.0f) ? wsum : 1.0f;
        const float val = a / divisor;
        const float nw = is_zero ? val : fmaf(0.1f, val, 0.9f * m);
        out[c * FEAT_CH + k] = (cnt > 0.0f) ? nw : m;
    }
}

extern "C" void kernel_launch(void* const* d_in, const int* in_sizes, int n_in,
                              void* d_out, int out_size, void* d_ws, size_t ws_size,
                              hipStream_t stream) {
    const float* feats  = (const float*)d_in[0];   // (1,64,120,120) f32
    const float* memory = (const float*)d_in[1];   // (124,1,64) f32
    const int*   seg    = (const int*)d_in[2];     // (1,480,480) i32
    float* out = (float*)d_out;                    // (124,1,64) f32
    float* ws  = (float*)d_ws;

    short* mn_bf = (short*)(ws + WS_MNBF);
    float* fT    = ws + WS_FT;
    float* part  = ws + WS_PART;

    k_prep<<<NTILE + NUM_CLASSES, 256, 0, stream>>>(memory, feats, mn_bf, fT);
    k_accum<<<NB, 512, 0, stream>>>(fT, seg, mn_bf, part);
    k_redfinal<<<NUM_CLASSES, 512, 0, stream>>>(part, memory, out);
}

// Round 12
// 136.959 us; speedup vs baseline: 1.8280x; 1.2666x over previous
//
#include <hip/hip_runtime.h>
#include <hip/hip_bf16.h>
#include <math.h>

#define NUM_CLASSES 124
#define NCLS_PAD    128
#define FEAT_CH     64
#define OUT_HW      480
#define IN_HW       120
#define NPIX        (OUT_HW * OUT_HW)
#define NCELL       (IN_HW * IN_HW)
#define NCHUNK      (NPIX / 32)         // 7200 chunks of 32 px
#define EPSV        1e-8f

#define STRIDE_ACC   65                 // LDS accumulator stride (floats)
#define ACC_FLOATS   (NCLS_PAD * STRIDE_ACC)           // 8320
#define PART_ROW     66                 // part slice: 64 ch + wsum + cnt per class
#define PART_SLICE   (NCLS_PAD * PART_ROW)             // 8448 floats
#define NB          450                 // 450*8 = 3600 waves -> exactly 2 chunks each
#define NTILE       (NCELL / 64)        // 225 transpose tiles

// ws layout (floats): mn_bf[7936 shorts] | fT[921600] | part[450*8448]
#define WS_MNBF 0
#define WS_FT   4096
#define WS_PART (WS_FT + NCELL * FEAT_CH)

typedef short  v8s __attribute__((ext_vector_type(8)));
typedef float  v4f __attribute__((ext_vector_type(4)));

__device__ __forceinline__ short f2bf(float x) {
    __hip_bfloat16 h = __float2bfloat16(x);
    return __builtin_bit_cast(short, h);
}
__device__ __forceinline__ float bf2f(short s) {
    return __int_as_float(((int)s) << 16);
}

template <int CTRL>
__device__ __forceinline__ float dpp_ror_add(float x) {
    int v = __builtin_amdgcn_update_dpp(0, __float_as_int(x), CTRL, 0xF, 0xF, false);
    return x + __int_as_float(v);
}
__device__ __forceinline__ void reduce16_pair(float& a, float& b) {
    a = dpp_ror_add<0x128>(a); b = dpp_ror_add<0x128>(b);   // row_ror:8
    a = dpp_ror_add<0x124>(a); b = dpp_ror_add<0x124>(b);   // row_ror:4
    a = dpp_ror_add<0x122>(a); b = dpp_ror_add<0x122>(b);   // row_ror:2
    a = dpp_ror_add<0x121>(a); b = dpp_ror_add<0x121>(b);   // row_ror:1
}

// ---- phase 0: LDS-tiled transpose feats -> fT; normalize memory -> mn (bf16) -
__global__ __launch_bounds__(256) void k_prep(
        const float* __restrict__ mem, const float* __restrict__ feats,
        short* __restrict__ mn_bf, float* __restrict__ fT) {
    const int b = blockIdx.x;
    if (b < NTILE) {
        __shared__ float tileL[64 * 65];
        const int q0 = b * 64;
        const int tid = threadIdx.x;
#pragma unroll
        for (int i = 0; i < 16; ++i) {
            const int idx = i * 256 + tid;
            const int k = idx >> 6, q = idx & 63;  // q fast -> coalesced read
            tileL[q * 65 + k] = feats[k * NCELL + q0 + q];
        }
        __syncthreads();
#pragma unroll
        for (int i = 0; i < 16; ++i) {
            const int idx = i * 256 + tid;
            const int q = idx >> 6, k = idx & 63;  // k fast -> coalesced write
            fT[(q0 + q) * FEAT_CH + k] = tileL[q * 65 + k];
        }
    } else {
        if (threadIdx.x < FEAT_CH) {
            const int c = b - NTILE;               // 0..123
            float v = mem[c * FEAT_CH + threadIdx.x];
            float s = v * v;
#pragma unroll
            for (int off = 32; off; off >>= 1) s += __shfl_xor(s, off);
            mn_bf[c * FEAT_CH + threadIdx.x] = f2bf(v / fmaxf(sqrtf(s), EPSV));
        }
    }
}

// ---- phase 1: one-hot MFMA accumulation; plain part-slice stores -------------
__global__ __launch_bounds__(512, 2) void k_accum(
        const float* __restrict__ fT, const int* __restrict__ seg,
        const short* __restrict__ mn_bf, float* __restrict__ part) {
    __shared__ float accL[ACC_FLOATS];                 // 33280 B
    __shared__ short mnL[NUM_CLASSES * 65];            // 16120 B, stride 65 shorts
    __shared__ float cntL[NCLS_PAD];

    const int tid = threadIdx.x;
    for (int i = tid; i < ACC_FLOATS; i += 512) accL[i] = 0.0f;
    for (int i = tid; i < NUM_CLASSES * FEAT_CH; i += 512)
        mnL[(i >> 6) * 65 + (i & 63)] = mn_bf[i];
    if (tid < NCLS_PAD) cntL[tid] = 0.0f;
    __syncthreads();

    const int lane = tid & 63;
    const int n  = lane & 15;         // ch within tile / class within band
    const int kg = lane >> 4;         // pixel-group (8 px each)
    const int widx = tid >> 6;        // wave in block (0..7)
    const int gwave = blockIdx.x * 8 + widx;

    v4f accR[8][4];
#pragma unroll
    for (int b = 0; b < 8; ++b)
#pragma unroll
        for (int t = 0; t < 4; ++t) accR[b][t] = (v4f)0.0f;

    for (int ch = gwave; ch < NCHUNK; ch += NB * 8) {   // exactly 2 iterations
        const int oy  = ch / 15;
        const int px0 = (ch - oy * 15) * 32 + kg * 8;
        float fy = fminf(fmaxf(oy * 0.25f - 0.375f, 0.0f), 119.0f);
        const int y0 = (int)fy; const float ty = fy - (float)y0;
        const int y1 = min(y0 + 1, IN_HW - 1);
        const int base = px0 >> 2;
        const int c0 = max(base - 1, 0), c1 = base;
        const int c2 = min(base + 1, IN_HW - 1), c3 = min(base + 2, IN_HW - 1);
        const int r0 = y0 * IN_HW, r1 = y1 * IN_HW;

        int segj[8];
        {
            const int4* sp = (const int4*)(seg + oy * OUT_HW + px0);
            int4 s0 = sp[0], s1 = sp[1];
            segj[0]=s0.x; segj[1]=s0.y; segj[2]=s0.z; segj[3]=s0.w;
            segj[4]=s1.x; segj[5]=s1.y; segj[6]=s1.z; segj[7]=s1.w;
        }
        float txj[8]; int Lj[8];
#pragma unroll
        for (int j = 0; j < 8; ++j) {
            float fx = fminf(fmaxf((float)(px0 + j) * 0.25f - 0.375f, 0.0f), 119.0f);
            int x0 = (int)fx; txj[j] = fx - (float)x0; Lj[j] = x0 - base + 1;  // 0..2
        }

        float nr[8], dt[8];
#pragma unroll
        for (int j = 0; j < 8; ++j) { nr[j] = 0.0f; dt[j] = 0.0f; }
        v8s Bfrag[4];
#pragma unroll
        for (int t = 0; t < 4; ++t) {
            const int chn = n + 16 * t;
            const float T0 = fT[(r0+c0)*64+chn], T1 = fT[(r0+c1)*64+chn];
            const float T2 = fT[(r0+c2)*64+chn], T3 = fT[(r0+c3)*64+chn];
            const float B0 = fT[(r1+c0)*64+chn], B1 = fT[(r1+c1)*64+chn];
            const float B2 = fT[(r1+c2)*64+chn], B3 = fT[(r1+c3)*64+chn];
#pragma unroll
            for (int j = 0; j < 8; ++j) {
                const int L = Lj[j];
                float tl = (L==0)?T0:((L==1)?T1:T2);
                float tr = (L==0)?T1:((L==1)?T2:T3);
                float bl = (L==0)?B0:((L==1)?B1:B2);
                float br = (L==0)?B1:((L==1)?B2:B3);
                float top = fmaf(txj[j], tr - tl, tl);
                float bot = fmaf(txj[j], br - bl, bl);
                float v   = fmaf(ty, bot - top, top);
                nr[j] = fmaf(v, v, nr[j]);
                dt[j] = fmaf(v, bf2f(mnL[segj[j] * 65 + chn]), dt[j]);
                Bfrag[t][j] = f2bf(v);
            }
        }
#pragma unroll
        for (int j = 0; j < 8; ++j) reduce16_pair(nr[j], dt[j]);

        float wj[8]; short wb[8];
#pragma unroll
        for (int j = 0; j < 8; ++j) {
            wj[j] = 1.0f - dt[j] / fmaxf(sqrtf(nr[j]), EPSV);  // mn==0 rows -> w==1
            wb[j] = f2bf(wj[j]);
        }
#pragma unroll
        for (int b = 0; b < 8; ++b) {
            v8s A;
#pragma unroll
            for (int j = 0; j < 8; ++j)
                A[j] = (segj[j] == b * 16 + n) ? wb[j] : (short)0;
#pragma unroll
            for (int t = 0; t < 4; ++t)
                accR[b][t] = __builtin_amdgcn_mfma_f32_16x16x32_bf16(A, Bfrag[t], accR[b][t], 0, 0, 0);
        }
        if (n == 0) {
#pragma unroll
            for (int j = 0; j < 8; ++j) {
                atomicAdd(&accL[segj[j] * STRIDE_ACC + FEAT_CH], wj[j]);
                atomicAdd(&cntL[segj[j]], 1.0f);
            }
        }
    }
    __syncthreads();

    // staggered band merge with STATIC register indexing:
    // step s: wave widx merges band b where (b - widx) & 7 == s (disjoint bands).
    // b is a compile-time constant in every accR[b] reference -> no scratch spill.
    for (int s = 0; s < 8; ++s) {
#pragma unroll
        for (int b = 0; b < 8; ++b) {
            if (((b - widx) & 7) == s) {       // wave-uniform guard
#pragma unroll
                for (int t = 0; t < 4; ++t)
#pragma unroll
                    for (int r = 0; r < 4; ++r) {
                        const int cls = b * 16 + kg * 4 + r;
                        const int chn = t * 16 + n;
                        accL[cls * STRIDE_ACC + chn] += accR[b][t][r];
                    }
            }
        }
        __syncthreads();
    }

    // plain coalesced store of this block's partial (stride-66: ch[64], wsum, cnt)
    float* __restrict__ dst = part + (size_t)blockIdx.x * PART_SLICE;
    for (int idx = tid; idx < PART_SLICE; idx += 512) {
        const int c = idx / PART_ROW, k = idx - c * PART_ROW;
        dst[idx] = (k < 65) ? accL[c * STRIDE_ACC + k] : cntL[c];
    }
}

// ---- phase 2 (fused): reduce 450 partials + momentum / is_zero / present -----
__global__ __launch_bounds__(512) void k_redfinal(
        const float* __restrict__ part, const float* __restrict__ mem,
        float* __restrict__ out) {
    __shared__ float sumL[8 * 64];
    __shared__ float extraL[16];
    const int c = blockIdx.x;                  // class
    const int tid = threadIdx.x;
    const int lane = tid & 63, p8 = tid >> 6;  // p8 in 0..7

    float sa = 0.0f;
    for (int p = p8; p < NB; p += 8)
        sa += part[(size_t)p * PART_SLICE + c * PART_ROW + lane];
    sumL[p8 * 64 + lane] = sa;
    if (tid < 16) {
        const int pb = tid & 7, slot = 64 + (tid >> 3);   // 64=wsum, 65=cnt
        float s = 0.0f;
        for (int p = pb; p < NB; p += 8)
            s += part[(size_t)p * PART_SLICE + c * PART_ROW + slot];
        extraL[tid] = s;
    }
    __syncthreads();

    if (tid < 64) {
        const int k = tid;
        float a = 0.0f;
#pragma unroll
        for (int q = 0; q < 8; ++q) a += sumL[q * 64 + k];
        float wsum = 0.0f, cnt = 0.0f;
#pragma unroll
        for (int q = 0; q < 8; ++q) { wsum += extraL[q]; cnt += extraL[8 + q]; }
        const float m = mem[c * FEAT_CH + k];
        const int is_zero = __all(m == 0.0f);           // full wave = the 64 channels
        const float divisor = (wsum > 0.0f) ? wsum : 1.0f;
        const float val = a / divisor;
        const float nw = is_zero ? val : fmaf(0.1f, val, 0.9f * m);
        out[c * FEAT_CH + k] = (cnt > 0.0f) ? nw : m;
    }
}

extern "C" void kernel_launch(void* const* d_in, const int* in_sizes, int n_in,
                              void* d_out, int out_size, void* d_ws, size_t ws_size,
                              hipStream_t stream) {
    const float* feats  = (const float*)d_in[0];   // (1,64,120,120) f32
    const float* memory = (const float*)d_in[1];   // (124,1,64) f32
    const int*   seg    = (const int*)d_in[2];     // (1,480,480) i32
    float* out = (float*)d_out;                    // (124,1,64) f32
    float* ws  = (float*)d_ws;

    short* mn_bf = (short*)(ws + WS_MNBF);
    float* fT    = ws + WS_FT;
    float* part  = ws + WS_PART;

    k_prep<<<NTILE + NUM_CLASSES, 256, 0, stream>>>(memory, feats, mn_bf, fT);
    k_accum<<<NB, 512, 0, stream>>>(fT, seg, mn_bf, part);
    k_redfinal<<<NUM_CLASSES, 512, 0, stream>>>(part, memory, out);
}